// Round 2
// baseline (227.946 us; speedup 1.0000x reference)
//
#include <hip/hip_runtime.h>

// ---------------------------------------------------------------------------
// HIDecoder fused: y=z@Wy^T+by ; lin_{m,v}=einsum(gamma,W{m,v})+b ; gaussian
// log-lik epilogue.  gamma never materialized:
//   Weff[n=t*8+j][k] = sum_y M_j[t][y]*Wy[t*32+y][k],  M_j = Wm(j<4)/Wv(j>=4)
//   beff[n]          = b_j[t,d] + sum_y by[t*32+y]*M_j[t][y]
// => one (32768 x 512 x 256) bf16-MFMA GEMM + elementwise epilogue.
// Columns: n = t*8+j ; j in [0,4) -> lin_m[d=j] ; j in [4,8) -> lin_v[d=j-4].
// ---------------------------------------------------------------------------

#define Bsz   32768
#define Tsz   64
#define Dsz   4
#define Ysz   32
#define Zsz   256
#define Nsz   512
#define BTtot (Bsz * Tsz)
#define EPS_  1e-3f
#define LOG2PI_ 1.8378770664093453f

#define BM       16            // batch rows per block
#define ASTRIDE  264           // ushorts per staged-z row (528 B, 16B-aligned)
#define LSTRIDE  528           // ushorts per lin row (1056 B = 66*16, 16B-aligned)

typedef __attribute__((ext_vector_type(4))) float  f32x4;
typedef __attribute__((ext_vector_type(8))) short  short8;
typedef __attribute__((ext_vector_type(2))) unsigned int uint2v;

static __device__ __forceinline__ unsigned short f2bf(float f) {
    unsigned int u = __float_as_uint(f);
    return (unsigned short)((u + 0x7fffu + ((u >> 16) & 1u)) >> 16);   // RNE
}
static __device__ __forceinline__ float bf2f(unsigned short h) {
    return __uint_as_float(((unsigned int)h) << 16);
}

// ---------------------------------------------------------------------------
// Prep: 64 blocks (one per t) x 256 threads (one per k).
// Each block reads its 32 Wy rows ONCE into registers, reuses for 8 columns.
// ---------------------------------------------------------------------------
__global__ __launch_bounds__(256)
void hidec_prep(const float* __restrict__ Wy, const float* __restrict__ by,
                const float* __restrict__ Wm, const float* __restrict__ bm,
                const float* __restrict__ Wv, const float* __restrict__ bv,
                unsigned short* __restrict__ weff, float* __restrict__ beff) {
    __shared__ float Ml[8][Ysz];
    __shared__ float byl[Ysz];
    const int t   = blockIdx.x;          // 0..63
    const int tid = threadIdx.x;
    {
        int j = tid >> 5, y = tid & 31;  // 8*32 = 256 loads
        const float* src = (j < 4) ? Wm : Wv;
        Ml[j][y] = src[(t * Dsz + (j & 3)) * Ysz + y];
    }
    if (tid < Ysz) byl[tid] = by[t * Ysz + tid];
    __syncthreads();

    const int k = tid;
    float wy[Ysz];
#pragma unroll
    for (int y = 0; y < Ysz; ++y)
        wy[y] = Wy[(size_t)(t * Ysz + y) * Zsz + k];
#pragma unroll
    for (int j = 0; j < 8; ++j) {
        float acc = 0.f;
#pragma unroll
        for (int y = 0; y < Ysz; ++y) acc = fmaf(Ml[j][y], wy[y], acc);
        weff[(size_t)(t * 8 + j) * Zsz + k] = f2bf(acc);
    }
    if (tid < 8) {
        int d = tid & 3;
        float s = ((tid < 4) ? bm : bv)[t * Dsz + d];
        for (int y = 0; y < Ysz; ++y) s = fmaf(byl[y], Ml[tid][y], s);
        beff[t * 8 + tid] = s;
    }
}

// ---------------------------------------------------------------------------
// Main: 2048 blocks x 256 threads (4 waves). Wave w owns cols [w*128,(w+1)*128).
// LDS: buf aliases {staged z bf16 (8448 B)} then {lin bf16 (16896 B)}.
// ---------------------------------------------------------------------------
__global__ __launch_bounds__(256, 6)
void hidec_main(const float* __restrict__ z, const float* __restrict__ bx,
                const int* __restrict__ miss, const float* __restrict__ dmean,
                const float* __restrict__ dvarp, const unsigned short* __restrict__ weff,
                const float* __restrict__ beff, float* __restrict__ out) {
    __shared__ unsigned short buf[BM * LSTRIDE];       // 16896 B (aliased a_lds/lin)
    __shared__ float4 sqA[Tsz], dmA[Tsz], dcA[Tsz];    // per-(t,·) constants
    __shared__ float  sldv[Tsz];                       // sum_d log(dvar_clamped)

    const int tid  = threadIdx.x;
    const long row0 = (long)blockIdx.x * BM;

    // ---- per-(t,d) constants (first wave; overlaps staging loads) ---------
    if (tid < Tsz) {
        float4 dv4 = *(const float4*)(dvarp + tid * 4);
        float4 dm4 = *(const float4*)(dmean + tid * 4);
        float d0 = fmaxf(dv4.x, EPS_), d1 = fmaxf(dv4.y, EPS_);
        float d2 = fmaxf(dv4.z, EPS_), d3 = fmaxf(dv4.w, EPS_);
        sqA[tid] = (float4){sqrtf(d0), sqrtf(d1), sqrtf(d2), sqrtf(d3)};
        dmA[tid] = dm4;
        dcA[tid] = (float4){d0, d1, d2, d3};
        sldv[tid] = __logf(d0) + __logf(d1) + __logf(d2) + __logf(d3);
    }

    // ---- stage z (16 x 256 fp32) -> bf16 LDS ------------------------------
    unsigned short* a_lds = buf;
#pragma unroll
    for (int i = 0; i < 4; ++i) {
        int idx4 = tid + i * 256;        // 1024 float4-groups
        int r  = idx4 >> 6;
        int c4 = idx4 & 63;
        float4 v = *(const float4*)(z + (row0 + r) * Zsz + c4 * 4);
        uint2v p;
        p.x = (unsigned)f2bf(v.x) | ((unsigned)f2bf(v.y) << 16);
        p.y = (unsigned)f2bf(v.z) | ((unsigned)f2bf(v.w) << 16);
        *(uint2v*)&a_lds[r * ASTRIDE + c4 * 4] = p;
    }
    __syncthreads();

    // ---- GEMM: 16 x 512 x K=256, bf16 MFMA 16x16x32 -----------------------
    const int lane = tid & 63;
    const int w    = tid >> 6;
    const int c    = lane & 15;
    const int q    = lane >> 4;

    f32x4 acc[8];
#pragma unroll
    for (int i = 0; i < 8; ++i) acc[i] = (f32x4){0.f, 0.f, 0.f, 0.f};

#pragma unroll
    for (int kk = 0; kk < 8; ++kk) {
        short8 a = *(const short8*)&a_lds[c * ASTRIDE + kk * 32 + q * 8];
#pragma unroll
        for (int nni = 0; nni < 8; ++nni) {
            int n = w * 128 + nni * 16 + c;
            short8 b = *(const short8*)(weff + (size_t)n * Zsz + kk * 32 + q * 8);
            acc[nni] = __builtin_amdgcn_mfma_f32_16x16x32_bf16(a, b, acc[nni], 0, 0, 0);
        }
    }
    __syncthreads();                       // all waves done reading a_lds

    // ---- write lin (bf16) into aliased buf --------------------------------
    // C layout: col(n-offset) = lane&15, row(m) = quad*4 + reg
    unsigned short* lin = buf;
#pragma unroll
    for (int nni = 0; nni < 8; ++nni) {
        int n = w * 128 + nni * 16 + c;
        float bb = beff[n];
        int t = n >> 3;
        int j = n & 7;
#pragma unroll
        for (int reg = 0; reg < 4; ++reg) {
            int r = q * 4 + reg;
            lin[r * LSTRIDE + t * 8 + j] = f2bf(acc[nni][reg] + bb);
        }
    }
    __syncthreads();

    // ---- epilogue: 16 rows x 64 t = 1024 tasks, 4 per thread --------------
#pragma unroll
    for (int pp = 0; pp < 4; ++pp) {
        int task = pp * 256 + tid;
        int t = task & 63;                 // == lane
        int r = task >> 6;
        long bt = (row0 + r) * Tsz + t;

        short8 l8 = *(const short8*)&lin[r * LSTRIDE + t * 8];
        float lm[4], lv[4];
#pragma unroll
        for (int d = 0; d < 4; ++d) {
            lm[d] = bf2f((unsigned short)l8[d]);
            lv[d] = bf2f((unsigned short)l8[4 + d]);
        }

        float4 x4  = *(const float4*)(bx + bt * 4);
        float4 sq4 = sqA[t];
        float4 dm4 = dmA[t];
        float4 dc4 = dcA[t];
        float xa[4]  = {x4.x,  x4.y,  x4.z,  x4.w};
        float sqa[4] = {sq4.x, sq4.y, sq4.z, sq4.w};
        float dma[4] = {dm4.x, dm4.y, dm4.z, dm4.w};
        float dca[4] = {dc4.x, dc4.y, dc4.z, dc4.w};

        float mean_o[4], var_o[4];
        float s = sldv[t];
        float evp = 1.f;
#pragma unroll
        for (int d = 0; d < 4; ++d) {
            float mean = fmaf(sqa[d], lm[d], dma[d]);
            float v    = lv[d];
            float sp   = fmaxf(v, 0.f) + __logf(1.f + __expf(-fabsf(v)));
            float ev   = fminf(fmaxf(sp, EPS_), 1e20f);
            float var  = dca[d] * ev;
            float diff = xa[d] - mean;
            s = fmaf(diff * diff, __builtin_amdgcn_rcpf(var), s);
            evp *= ev;
            mean_o[d] = mean;
            var_o[d]  = var;
        }
        s += __logf(evp);                  // == sum_d log(ev_d)
        float logp = -0.5f * (s + 4.f * LOG2PI_);
        float mk = (float)miss[bt];

        float lx = logp * mk;
        out[bt]         = lx;              // log_p_x
        out[BTtot + bt] = logp - lx;       // log_p_x_missing

        *(float4*)(out + 2L * BTtot + bt * 4) =
            (float4){mean_o[0], mean_o[1], mean_o[2], mean_o[3]};
        *(float4*)(out + 6L * BTtot + bt * 4) =
            (float4){var_o[0], var_o[1], var_o[2], var_o[3]};
    }
}

// ---------------------------------------------------------------------------
extern "C" void kernel_launch(void* const* d_in, const int* in_sizes, int n_in,
                              void* d_out, int out_size, void* d_ws, size_t ws_size,
                              hipStream_t stream) {
    const float* z     = (const float*)d_in[0];
    const float* bx    = (const float*)d_in[1];
    const int*   miss  = (const int*)d_in[2];
    const float* dmean = (const float*)d_in[3];
    const float* dvar  = (const float*)d_in[4];
    const float* Wy    = (const float*)d_in[5];
    const float* by    = (const float*)d_in[6];
    const float* Wm    = (const float*)d_in[7];
    const float* bm    = (const float*)d_in[8];
    const float* Wv    = (const float*)d_in[9];
    const float* bv    = (const float*)d_in[10];
    float* out = (float*)d_out;

    unsigned short* weff = (unsigned short*)d_ws;                    // 256 KiB
    float* beff = (float*)((char*)d_ws + (size_t)Nsz * Zsz * 2);     // + 2 KiB

    hidec_prep<<<Tsz, Zsz, 0, stream>>>(Wy, by, Wm, bm, Wv, bv, weff, beff);
    hidec_main<<<Bsz / BM, 256, 0, stream>>>(z, bx, miss, dmean, dvar, weff, beff, out);
}

// Round 3
// 175.263 us; speedup vs baseline: 1.3006x; 1.3006x over previous
//
#include <hip/hip_runtime.h>

// ---------------------------------------------------------------------------
// HIDecoder fused: y=z@Wy^T+by ; lin_{m,v}=einsum(gamma,W{m,v})+b ; gaussian
// log-lik epilogue.  gamma never materialized:
//   Weff[n=t*8+j][k] = sum_y M_j[t][y]*Wy[t*32+y][k],  M_j = Wm(j<4)/Wv(j>=4)
//   beff[n]          = b_j[t,d] + sum_y by[t*32+y]*M_j[t][y]
// => one (32768 x 512 x 256) bf16-MFMA GEMM + elementwise epilogue.
//
// R3: weff stored PRE-SWIZZLED in MFMA B-fragment order [tau][kk][lane][8bf16]
// so each b-load is one contiguous 1KB wave transaction; BM=64 so each block
// reads weff exactly once (b-frags register-resident across 4 row-tiles).
// Total weff L2 traffic: 512MB -> 128MB, dense.
// ---------------------------------------------------------------------------

#define Bsz   32768
#define Tsz   64
#define Dsz   4
#define Ysz   32
#define Zsz   256
#define Nsz   512
#define BTtot (Bsz * Tsz)
#define EPS_  1e-3f
#define LOG2PI_ 1.8378770664093453f

#define BM       64            // batch rows per block
#define NT       512           // threads per block (8 waves)
#define ASTRIDE  264           // ushorts per staged-z row
#define LSTRIDE  528           // ushorts per lin row (32-row chunk)

typedef __attribute__((ext_vector_type(4))) float  f32x4;
typedef __attribute__((ext_vector_type(8))) short  short8;
typedef __attribute__((ext_vector_type(2))) unsigned int uint2v;

static __device__ __forceinline__ unsigned short f2bf(float f) {
    unsigned int u = __float_as_uint(f);
    return (unsigned short)((u + 0x7fffu + ((u >> 16) & 1u)) >> 16);   // RNE
}
static __device__ __forceinline__ float bf2f(unsigned short h) {
    return __uint_as_float(((unsigned int)h) << 16);
}

// ---------------------------------------------------------------------------
// Prep: 64 blocks (one per t) x 256 threads (one per k).
// Writes weff in B-fragment order:
//   addr(n,k) = (((tau*8+kk)*4+q)*16+c)*8 + j,  tau=n>>4, c=n&15,
//   kk=k>>5, q=(k>>3)&3, j=k&7
// so wave load for (tau,kk) is weff + (tau*8+kk)*512 + lane*8 (contiguous 1KB).
// ---------------------------------------------------------------------------
__global__ __launch_bounds__(256)
void hidec_prep(const float* __restrict__ Wy, const float* __restrict__ by,
                const float* __restrict__ Wm, const float* __restrict__ bm,
                const float* __restrict__ Wv, const float* __restrict__ bv,
                unsigned short* __restrict__ weff, float* __restrict__ beff) {
    __shared__ float Ml[8][Ysz];
    __shared__ float byl[Ysz];
    const int t   = blockIdx.x;          // 0..63
    const int tid = threadIdx.x;
    {
        int j = tid >> 5, y = tid & 31;
        const float* src = (j < 4) ? Wm : Wv;
        Ml[j][y] = src[(t * Dsz + (j & 3)) * Ysz + y];
    }
    if (tid < Ysz) byl[tid] = by[t * Ysz + tid];
    __syncthreads();

    const int k = tid;                   // 0..255
    const int kk = k >> 5, q = (k >> 3) & 3, je = k & 7;
    float wy[Ysz];
#pragma unroll
    for (int y = 0; y < Ysz; ++y)
        wy[y] = Wy[(size_t)(t * Ysz + y) * Zsz + k];
#pragma unroll
    for (int j = 0; j < 8; ++j) {
        float acc = 0.f;
#pragma unroll
        for (int y = 0; y < Ysz; ++y) acc = fmaf(Ml[j][y], wy[y], acc);
        int n   = t * 8 + j;
        int tau = n >> 4, c = n & 15;
        weff[((((tau * 8 + kk) * 4 + q) * 16 + c) * 8) + je] = f2bf(acc);
    }
    if (tid < 8) {
        int d = tid & 3;
        float s = ((tid < 4) ? bm : bv)[t * Dsz + d];
        for (int y = 0; y < Ysz; ++y) s = fmaf(byl[y], Ml[tid][y], s);
        beff[t * 8 + tid] = s;
    }
}

// ---------------------------------------------------------------------------
// Main: 512 blocks x 512 threads (8 waves). Wave w owns col-tiles w*4..w*4+3
// (cols w*64..w*64+63) for all 4 row-tiles of 16 (BM=64).
// ---------------------------------------------------------------------------
__global__ __launch_bounds__(NT, 4)
void hidec_main(const float* __restrict__ z, const float* __restrict__ bx,
                const int* __restrict__ miss, const float* __restrict__ dmean,
                const float* __restrict__ dvarp, const unsigned short* __restrict__ weff,
                const float* __restrict__ beff, float* __restrict__ out) {
    __shared__ unsigned short buf[BM * ASTRIDE];       // 33792 B; aliased a_lds / lin(32 rows)
    __shared__ float4 sqA[Tsz], dmA[Tsz], dcA[Tsz];
    __shared__ float  sldv[Tsz];
    __shared__ float  beffL[Nsz];

    const int tid  = threadIdx.x;
    const long row0 = (long)blockIdx.x * BM;

    // ---- per-(t,d) constants + beff copy ----------------------------------
    if (tid < Tsz) {
        float4 dv4 = *(const float4*)(dvarp + tid * 4);
        float4 dm4 = *(const float4*)(dmean + tid * 4);
        float d0 = fmaxf(dv4.x, EPS_), d1 = fmaxf(dv4.y, EPS_);
        float d2 = fmaxf(dv4.z, EPS_), d3 = fmaxf(dv4.w, EPS_);
        sqA[tid] = (float4){sqrtf(d0), sqrtf(d1), sqrtf(d2), sqrtf(d3)};
        dmA[tid] = dm4;
        dcA[tid] = (float4){d0, d1, d2, d3};
        sldv[tid] = __logf(d0) + __logf(d1) + __logf(d2) + __logf(d3);
    }
    beffL[tid] = beff[tid];   // NT==512==Nsz

    // ---- stage z (64 x 256 fp32) -> bf16 LDS ------------------------------
    unsigned short* a_lds = buf;
#pragma unroll
    for (int i = 0; i < 8; ++i) {
        int idx4 = tid + i * NT;         // 4096 float4-groups
        int r  = idx4 >> 6;
        int c4 = idx4 & 63;
        float4 v = *(const float4*)(z + (row0 + r) * Zsz + c4 * 4);
        uint2v p;
        p.x = (unsigned)f2bf(v.x) | ((unsigned)f2bf(v.y) << 16);
        p.y = (unsigned)f2bf(v.z) | ((unsigned)f2bf(v.w) << 16);
        *(uint2v*)&a_lds[r * ASTRIDE + c4 * 4] = p;
    }
    __syncthreads();

    // ---- GEMM: 64 x 512 x K=256, bf16 MFMA 16x16x32 -----------------------
    const int lane = tid & 63;
    const int w    = tid >> 6;           // wave 0..7
    const int c    = lane & 15;
    const int q    = lane >> 4;

    f32x4 acc[16];                       // [ti*4 + rt]
#pragma unroll
    for (int i = 0; i < 16; ++i) acc[i] = (f32x4){0.f, 0.f, 0.f, 0.f};

    // b-fragment base: tau0 = w*4 ; per-(tau,kk) block = 512 ushorts
    const unsigned short* wp = weff + ((size_t)(w * 4) * 8) * 512 + lane * 8;

#pragma unroll
    for (int kk = 0; kk < 8; ++kk) {
        short8 b0 = *(const short8*)(wp + kk * 512 + 0 * 4096);
        short8 b1 = *(const short8*)(wp + kk * 512 + 1 * 4096);
        short8 b2 = *(const short8*)(wp + kk * 512 + 2 * 4096);
        short8 b3 = *(const short8*)(wp + kk * 512 + 3 * 4096);
        short8 a0 = *(const short8*)&a_lds[(0 * 16 + c) * ASTRIDE + kk * 32 + q * 8];
        short8 a1 = *(const short8*)&a_lds[(1 * 16 + c) * ASTRIDE + kk * 32 + q * 8];
        short8 a2 = *(const short8*)&a_lds[(2 * 16 + c) * ASTRIDE + kk * 32 + q * 8];
        short8 a3 = *(const short8*)&a_lds[(3 * 16 + c) * ASTRIDE + kk * 32 + q * 8];
        acc[0]  = __builtin_amdgcn_mfma_f32_16x16x32_bf16(a0, b0, acc[0],  0, 0, 0);
        acc[1]  = __builtin_amdgcn_mfma_f32_16x16x32_bf16(a1, b0, acc[1],  0, 0, 0);
        acc[2]  = __builtin_amdgcn_mfma_f32_16x16x32_bf16(a2, b0, acc[2],  0, 0, 0);
        acc[3]  = __builtin_amdgcn_mfma_f32_16x16x32_bf16(a3, b0, acc[3],  0, 0, 0);
        acc[4]  = __builtin_amdgcn_mfma_f32_16x16x32_bf16(a0, b1, acc[4],  0, 0, 0);
        acc[5]  = __builtin_amdgcn_mfma_f32_16x16x32_bf16(a1, b1, acc[5],  0, 0, 0);
        acc[6]  = __builtin_amdgcn_mfma_f32_16x16x32_bf16(a2, b1, acc[6],  0, 0, 0);
        acc[7]  = __builtin_amdgcn_mfma_f32_16x16x32_bf16(a3, b1, acc[7],  0, 0, 0);
        acc[8]  = __builtin_amdgcn_mfma_f32_16x16x32_bf16(a0, b2, acc[8],  0, 0, 0);
        acc[9]  = __builtin_amdgcn_mfma_f32_16x16x32_bf16(a1, b2, acc[9],  0, 0, 0);
        acc[10] = __builtin_amdgcn_mfma_f32_16x16x32_bf16(a2, b2, acc[10], 0, 0, 0);
        acc[11] = __builtin_amdgcn_mfma_f32_16x16x32_bf16(a3, b2, acc[11], 0, 0, 0);
        acc[12] = __builtin_amdgcn_mfma_f32_16x16x32_bf16(a0, b3, acc[12], 0, 0, 0);
        acc[13] = __builtin_amdgcn_mfma_f32_16x16x32_bf16(a1, b3, acc[13], 0, 0, 0);
        acc[14] = __builtin_amdgcn_mfma_f32_16x16x32_bf16(a2, b3, acc[14], 0, 0, 0);
        acc[15] = __builtin_amdgcn_mfma_f32_16x16x32_bf16(a3, b3, acc[15], 0, 0, 0);
    }
    __syncthreads();                     // all waves done reading a_lds

    // ---- epilogue in 2 chunks of 32 rows (lin aliases a_lds) --------------
    unsigned short* lin = buf;
#pragma unroll
    for (int ch = 0; ch < 2; ++ch) {
        // write lin (bf16) for local rows [0,32) = global rows ch*32 + rl
        // C layout: col = lane&15 (within tile), row(m) = quad*4 + reg
#pragma unroll
        for (int ti = 0; ti < 4; ++ti) {
            int n  = (w * 4 + ti) * 16 + c;
            float bb = beffL[n];
            int t  = n >> 3;
            int jj = n & 7;
#pragma unroll
            for (int rh = 0; rh < 2; ++rh) {
                int rt = ch * 2 + rh;
#pragma unroll
                for (int reg = 0; reg < 4; ++reg) {
                    int rl = rh * 16 + q * 4 + reg;      // 0..31
                    lin[rl * LSTRIDE + t * 8 + jj] = f2bf(acc[ti * 4 + rt][reg] + bb);
                }
            }
        }
        __syncthreads();

        // postprocess 32 rows x 64 t = 2048 tasks, 4 per thread
#pragma unroll
        for (int pp = 0; pp < 4; ++pp) {
            int task = pp * NT + tid;
            int t  = task & 63;
            int rl = task >> 6;          // 0..31
            long bt = (row0 + ch * 32 + rl) * Tsz + t;

            short8 l8 = *(const short8*)&lin[rl * LSTRIDE + t * 8];
            float lm[4], lv[4];
#pragma unroll
            for (int d = 0; d < 4; ++d) {
                lm[d] = bf2f((unsigned short)l8[d]);
                lv[d] = bf2f((unsigned short)l8[4 + d]);
            }

            float4 x4  = *(const float4*)(bx + bt * 4);
            float4 sq4 = sqA[t];
            float4 dm4 = dmA[t];
            float4 dc4 = dcA[t];
            float xa[4]  = {x4.x,  x4.y,  x4.z,  x4.w};
            float sqa[4] = {sq4.x, sq4.y, sq4.z, sq4.w};
            float dma[4] = {dm4.x, dm4.y, dm4.z, dm4.w};
            float dca[4] = {dc4.x, dc4.y, dc4.z, dc4.w};

            float mean_o[4], var_o[4];
            float s = sldv[t];
            float evp = 1.f;
#pragma unroll
            for (int d = 0; d < 4; ++d) {
                float mean = fmaf(sqa[d], lm[d], dma[d]);
                float v    = lv[d];
                float sp   = fmaxf(v, 0.f) + __logf(1.f + __expf(-fabsf(v)));
                float ev   = fminf(fmaxf(sp, EPS_), 1e20f);
                float var  = dca[d] * ev;
                float diff = xa[d] - mean;
                s = fmaf(diff * diff, __builtin_amdgcn_rcpf(var), s);
                evp *= ev;
                mean_o[d] = mean;
                var_o[d]  = var;
            }
            s += __logf(evp);
            float logp = -0.5f * (s + 4.f * LOG2PI_);
            float mk = (float)miss[bt];

            float lx = logp * mk;
            out[bt]         = lx;              // log_p_x
            out[BTtot + bt] = logp - lx;       // log_p_x_missing

            *(float4*)(out + 2L * BTtot + bt * 4) =
                (float4){mean_o[0], mean_o[1], mean_o[2], mean_o[3]};
            *(float4*)(out + 6L * BTtot + bt * 4) =
                (float4){var_o[0], var_o[1], var_o[2], var_o[3]};
        }
        __syncthreads();                 // protect lin before next chunk
    }
}

// ---------------------------------------------------------------------------
extern "C" void kernel_launch(void* const* d_in, const int* in_sizes, int n_in,
                              void* d_out, int out_size, void* d_ws, size_t ws_size,
                              hipStream_t stream) {
    const float* z     = (const float*)d_in[0];
    const float* bx    = (const float*)d_in[1];
    const int*   miss  = (const int*)d_in[2];
    const float* dmean = (const float*)d_in[3];
    const float* dvar  = (const float*)d_in[4];
    const float* Wy    = (const float*)d_in[5];
    const float* by    = (const float*)d_in[6];
    const float* Wm    = (const float*)d_in[7];
    const float* bm    = (const float*)d_in[8];
    const float* Wv    = (const float*)d_in[9];
    const float* bv    = (const float*)d_in[10];
    float* out = (float*)d_out;

    unsigned short* weff = (unsigned short*)d_ws;                    // 256 KiB
    float* beff = (float*)((char*)d_ws + (size_t)Nsz * Zsz * 2);     // + 2 KiB

    hidec_prep<<<Tsz, Zsz, 0, stream>>>(Wy, by, Wm, bm, Wv, bv, weff, beff);
    hidec_main<<<Bsz / BM, NT, 0, stream>>>(z, bx, miss, dmean, dvar, weff, beff, out);
}